// Round 7
// baseline (453.798 us; speedup 1.0000x reference)
//
#include <hip/hip_runtime.h>
#include <hip/hip_cooperative_groups.h>
#include <hip/hip_bf16.h>
#include <math.h>

namespace cg = cooperative_groups;

#define N_NODES 50000
#define N_EDGES 640000
#define HEADS 4
#define CDIM 32
#define HC 128          // HEADS*CDIM
#define DIN 128
#define DOUT 32
#define NEG_SLOPE 0.2f
#define TPAD 136        // 128 + 8 bf16 pad -> 2-way bank aliasing (free)
#define BCAP 64         // bucket capacity; P(deg>64)~1e-17 for Binom(640K,1/50K)
#define NPB 16          // nodes per agg unit (4 waves x 4 sequential)
#define EPT 4           // edges per fill thread
#define ZERO_NB ((N_NODES + 255) / 256)             // 196
#define WT_NB (2 * DIN * HC / 256)                  // 128
#define WPT_NB (DOUT * HC / 256)                    // 16
#define PREP_UNITS (ZERO_NB + WT_NB + WPT_NB + 1)   // 341
#define FILL_NB (N_EDGES / (256 * EPT))             // 625 (exact)
#define TF_NB ((N_NODES + 127) / 128)               // 391 (2 nodes/thread)
#define P1_UNITS (FILL_NB + TF_NB)                  // 1016
#define AGG_NB (N_NODES / NPB)                      // 3125 agg units

typedef __hip_bfloat16 bf16;
typedef __attribute__((ext_vector_type(8))) short short8;
typedef __attribute__((ext_vector_type(4))) float floatx4;
typedef __attribute__((ext_vector_type(4))) unsigned short ushort4v;

static __device__ __forceinline__ float bflo(unsigned w) { return __uint_as_float(w << 16); }
static __device__ __forceinline__ float bfhi(unsigned w) { return __uint_as_float(w & 0xFFFF0000u); }
static __device__ __forceinline__ unsigned short f2bf(float f) {
    union { bf16 h; unsigned short u; } cv; cv.h = __float2bfloat16(f); return cv.u;
}

// ===================== shared phase-unit bodies =====================
// Used identically by the cooperative kernel AND the 3-kernel fallback,
// so both paths have provably identical semantics.

static __device__ __forceinline__ void prep_unit(
    const int b, const int t,
    unsigned* __restrict__ cnt,
    const float* __restrict__ Wl, const float* __restrict__ Wr,
    const float* __restrict__ bias, const float* __restrict__ Wp,
    const float* __restrict__ bp,
    bf16* __restrict__ WlF, bf16* __restrict__ WrF, bf16* __restrict__ WpT,
    float* __restrict__ cvec, float (*part)[32])
{
    if (b < ZERO_NB) {
        const int i = b * 256 + t;
        if (i < N_NODES) cnt[i] = 0u;
    } else if (b < ZERO_NB + WT_NB) {
        const int i = (b - ZERO_NB) * 256 + t;      // [0, 32768)
        const int i2 = (i < DIN * HC) ? i : i - DIN * HC;
        const int c = i2 >> 7, j = i2 & 127;        // W[c][j]
        const int jt = j >> 4, m = j & 15;
        const int kk = c >> 5, quad = (c >> 3) & 3, u = c & 7;
        const int idx = (jt * 4 + kk) * 512 + (quad * 16 + m) * 8 + u;
        if (i < DIN * HC) WlF[idx] = __float2bfloat16(Wl[i2]);
        else              WrF[idx] = __float2bfloat16(Wr[i2]);
    } else if (b < ZERO_NB + WT_NB + WPT_NB) {
        const int i = (b - ZERO_NB - WT_NB) * 256 + t;  // [0, 4096)
        const int c = i >> 5, j = i & 31;           // Wp[c][j]
        WpT[j * HC + c] = __float2bfloat16(Wp[i]);
    } else {
        const int j = t & 31, ch = t >> 5;          // 8 chunks x 16 c's
        float v = 0.f;
        for (int c = ch * 16; c < ch * 16 + 16; c++)
            v += bias[c] * Wp[c * DOUT + j];
        part[ch][j] = v;
        __syncthreads();
        if (t < 32) {
            float s = bp[t];
            #pragma unroll
            for (int k = 0; k < 8; k++) s += part[k][t];
            cvec[t] = s;
        }
        __syncthreads();
    }
}

static __device__ __forceinline__ void fill_unit(
    const int b, const int t,
    const int* __restrict__ ei, unsigned* __restrict__ cnt,
    unsigned short* __restrict__ srcs)
{
    const int e0 = (b * 256 + t) * EPT;             // exact, no tail
    const int4 sv = *(const int4*)(ei + e0);
    const int4 dv = *(const int4*)(ei + N_EDGES + e0);
    const int s[4] = {sv.x, sv.y, sv.z, sv.w};
    const int d[4] = {dv.x, dv.y, dv.z, dv.w};
    unsigned pos[4];
    #pragma unroll
    for (int i = 0; i < EPT; i++)                   // independent far-atomics
        pos[i] = atomicAdd(&cnt[d[i]], 1u);
    #pragma unroll
    for (int i = 0; i < EPT; i++)
        if (pos[i] < BCAP)
            srcs[((size_t)d[i] << 6) + pos[i]] = (unsigned short)s[i];
}

static __device__ __forceinline__ void tf_unit(
    const int bt, const int t,
    const float* __restrict__ x,
    const bf16* __restrict__ WlF, const bf16* __restrict__ WrF,
    bf16* __restrict__ xl, bf16* __restrict__ xr)
{
    const int n0 = bt * 128;
    const int w = t >> 6, lane = t & 63;
    const int m = lane & 15, quad = lane >> 4;
    const int na = n0 + w * 32 + m;                 // nodes {w*32+m, +16}
    const int nb = na + 16;
    const bool va = (na < N_NODES), vb = (nb < N_NODES);

    const float* xpa = x + (size_t)(va ? na : 0) * DIN;
    const float* xpb = x + (size_t)(vb ? nb : 0) * DIN;
    short8 afa[4], afb[4];
    #pragma unroll
    for (int kk = 0; kk < 4; kk++) {
        const float4 la = *(const float4*)(xpa + kk * 32 + quad * 8);
        const float4 ha = *(const float4*)(xpa + kk * 32 + quad * 8 + 4);
        const float4 lb = *(const float4*)(xpb + kk * 32 + quad * 8);
        const float4 hb = *(const float4*)(xpb + kk * 32 + quad * 8 + 4);
        short8 va8, vb8;
        va8[0] = (short)f2bf(la.x); va8[1] = (short)f2bf(la.y);
        va8[2] = (short)f2bf(la.z); va8[3] = (short)f2bf(la.w);
        va8[4] = (short)f2bf(ha.x); va8[5] = (short)f2bf(ha.y);
        va8[6] = (short)f2bf(ha.z); va8[7] = (short)f2bf(ha.w);
        vb8[0] = (short)f2bf(lb.x); vb8[1] = (short)f2bf(lb.y);
        vb8[2] = (short)f2bf(lb.z); vb8[3] = (short)f2bf(lb.w);
        vb8[4] = (short)f2bf(hb.x); vb8[5] = (short)f2bf(hb.y);
        vb8[6] = (short)f2bf(hb.z); vb8[7] = (short)f2bf(hb.w);
        afa[kk] = va8;
        afb[kk] = vb8;
    }

    const short8* wlf = (const short8*)WlF;
    const short8* wrf = (const short8*)WrF;
    #pragma unroll
    for (int jt = 0; jt < 8; jt++) {
        floatx4 aLa = {0.f,0.f,0.f,0.f}, aLb = {0.f,0.f,0.f,0.f};
        floatx4 aRa = {0.f,0.f,0.f,0.f}, aRb = {0.f,0.f,0.f,0.f};
        #pragma unroll
        for (int kk = 0; kk < 4; kk++) {
            const short8 bl = wlf[(jt * 4 + kk) * 64 + lane];
            const short8 br = wrf[(jt * 4 + kk) * 64 + lane];
            aLa = __builtin_amdgcn_mfma_f32_16x16x32_bf16(bl, afa[kk], aLa, 0, 0, 0);
            aLb = __builtin_amdgcn_mfma_f32_16x16x32_bf16(bl, afb[kk], aLb, 0, 0, 0);
            aRa = __builtin_amdgcn_mfma_f32_16x16x32_bf16(br, afa[kk], aRa, 0, 0, 0);
            aRb = __builtin_amdgcn_mfma_f32_16x16x32_bf16(br, afb[kk], aRb, 0, 0, 0);
        }
        const int joff = jt * 16 + quad * 4;
        if (va) {
            ushort4v pl, pr;
            #pragma unroll
            for (int r = 0; r < 4; r++) { pl[r] = f2bf(aLa[r]); pr[r] = f2bf(aRa[r]); }
            *(ushort4v*)(xl + (size_t)na * HC + joff) = pl;
            *(ushort4v*)(xr + (size_t)na * HC + joff) = pr;
        }
        if (vb) {
            ushort4v pl, pr;
            #pragma unroll
            for (int r = 0; r < 4; r++) { pl[r] = f2bf(aLb[r]); pr[r] = f2bf(aRb[r]); }
            *(ushort4v*)(xl + (size_t)nb * HC + joff) = pl;
            *(ushort4v*)(xr + (size_t)nb * HC + joff) = pr;
        }
    }
}

// gather one edge's xl-row segment: broadcast src idx from lane (e&63),
// mask OOB edges to row 0 (valid, L2-hot).
static __device__ __forceinline__ uint4 gat(
    const int srcj, const int e, const int cn,
    const unsigned* __restrict__ xl2, const int hq)
{
    const int s = __shfl(srcj, e & 63, 64);
    const size_t row = (size_t)((e < cn) ? s : 0) << 6;
    return ((const uint4*)(xl2 + row))[hq];
}

static __device__ __forceinline__ void consume_edge(
    const uint4 bx, const int eidx, const int cn,
    const float* __restrict__ xr_, const float* __restrict__ a_,
    float& s_run, float* __restrict__ acc)
{
    float x_[8];
    x_[0] = bflo(bx.x); x_[1] = bfhi(bx.x);
    x_[2] = bflo(bx.y); x_[3] = bfhi(bx.y);
    x_[4] = bflo(bx.z); x_[5] = bfhi(bx.z);
    x_[6] = bflo(bx.w); x_[7] = bfhi(bx.w);
    float p = 0.f;
    #pragma unroll
    for (int k = 0; k < 8; k++) {
        float v = x_[k] + xr_[k];
        v = fmaxf(v, NEG_SLOPE * v);
        p = fmaf(a_[k], v, p);
    }
    p += __shfl_xor(p, 1, 64);
    p += __shfl_xor(p, 2, 64);          // per-head logit (4 hq lanes/head)
    const float e_ = (eidx < cn) ? __expf(p) : 0.f;
    s_run += e_;
    #pragma unroll
    for (int k = 0; k < 8; k++) acc[k] = fmaf(x_[k], e_, acc[k]);
}

static __device__ __forceinline__ void agg_unit(
    const int u, const int t, unsigned short (*srow)[TPAD],
    const unsigned short* __restrict__ srcs, const unsigned* __restrict__ cnt,
    const unsigned* __restrict__ xl2, const unsigned* __restrict__ xr2,
    const float* __restrict__ att, const bf16* __restrict__ WpT,
    const float* __restrict__ cvec, float* __restrict__ out)
{
    const int w = t >> 6, lane = t & 63;
    const int es = lane >> 4, hq = lane & 15;

    const float4 av0 = ((const float4*)att)[hq * 2];
    const float4 av1 = ((const float4*)att)[hq * 2 + 1];
    const float a_[8] = {av0.x, av0.y, av0.z, av0.w, av1.x, av1.y, av1.z, av1.w};

    const int nb0 = u * NPB + w * 4;                // wave's 4 nodes
    const uint4 cv4 = *(const uint4*)(cnt + nb0);   // 16B-aligned
    int cns[4];
    cns[0] = (int)(cv4.x < 64u ? cv4.x : 64u);
    cns[1] = (int)(cv4.y < 64u ? cv4.y : 64u);
    cns[2] = (int)(cv4.z < 64u ? cv4.z : 64u);
    cns[3] = (int)(cv4.w < 64u ? cv4.w : 64u);
    int srcjv[4];
    uint4 xru[4];
    #pragma unroll
    for (int ni = 0; ni < 4; ni++) {                // unguarded: srcs is [N][64]
        srcjv[ni] = (int)srcs[((size_t)(nb0 + ni) << 6) + lane];
        xru[ni] = ((const uint4*)(xr2 + (size_t)(nb0 + ni) * 64))[hq];
    }

    #pragma unroll
    for (int ni = 0; ni < 4; ni++) {
        const int cn = cns[ni];
        float xr_[8];
        xr_[0] = bflo(xru[ni].x); xr_[1] = bfhi(xru[ni].x);
        xr_[2] = bflo(xru[ni].y); xr_[3] = bfhi(xru[ni].y);
        xr_[4] = bflo(xru[ni].z); xr_[5] = bfhi(xru[ni].z);
        xr_[6] = bflo(xru[ni].w); xr_[7] = bfhi(xru[ni].w);
        float s_run = 0.f;
        float acc[8] = {0.f, 0.f, 0.f, 0.f, 0.f, 0.f, 0.f, 0.f};
        const int sj = srcjv[ni];

        uint4 b0 = gat(sj, es,      cn, xl2, hq);   // depth-4 prologue
        uint4 b1 = gat(sj, es + 4,  cn, xl2, hq);
        uint4 b2 = gat(sj, es + 8,  cn, xl2, hq);
        uint4 b3 = gat(sj, es + 12, cn, xl2, hq);
        for (int i = 0; i < cn; i += 16) {
            const bool more = (i + 16 < cn);        // wave-uniform
            consume_edge(b0, i + es,      cn, xr_, a_, s_run, acc);
            if (more) b0 = gat(sj, i + 16 + es, cn, xl2, hq);
            consume_edge(b1, i + es + 4,  cn, xr_, a_, s_run, acc);
            if (more) b1 = gat(sj, i + 20 + es, cn, xl2, hq);
            consume_edge(b2, i + es + 8,  cn, xr_, a_, s_run, acc);
            if (more) b2 = gat(sj, i + 24 + es, cn, xl2, hq);
            consume_edge(b3, i + es + 12, cn, xr_, a_, s_run, acc);
            if (more) b3 = gat(sj, i + 28 + es, cn, xl2, hq);
        }
        // combine the 4 edge slots
        s_run += __shfl_xor(s_run, 16, 64);
        s_run += __shfl_xor(s_run, 32, 64);
        #pragma unroll
        for (int k = 0; k < 8; k++) {
            acc[k] += __shfl_xor(acc[k], 16, 64);
            acc[k] += __shfl_xor(acc[k], 32, 64);
        }
        const float rden = 1.f / (s_run + 1e-16f);

        if (es == 0) {                  // lane hq stores cols 8hq..8hq+7 (16B)
            union { unsigned short s[8]; uint4 v; } pk;
            #pragma unroll
            for (int k = 0; k < 8; k++) pk.s[k] = f2bf(acc[k] * rden);
            *(uint4*)&srow[w * 4 + ni][hq * 8] = pk.v;
        }
    }
    __syncthreads();

    // ---- MFMA projection: D[16 nodes][32 cols] = srow @ Wp, j-tile = w
    if (w < 2) {
        const int m = lane & 15, quad = lane >> 4;
        short8 af[4];
        #pragma unroll
        for (int kk = 0; kk < 4; kk++)      // A row = node m, k = kk*32+quad*8
            af[kk] = *(const short8*)&srow[m][kk * 32 + quad * 8];
        floatx4 d = {0.f, 0.f, 0.f, 0.f};
        #pragma unroll
        for (int kk = 0; kk < 4; kk++) {
            const short8 bfr = *(const short8*)(WpT + (w * 16 + m) * HC + kk * 32 + quad * 8);
            d = __builtin_amdgcn_mfma_f32_16x16x32_bf16(af[kk], bfr, d, 0, 0, 0);
        }
        const int jj = w * 16 + m;
        const float cv = cvec[jj];
        #pragma unroll
        for (int r = 0; r < 4; r++) {       // D: col=m (j), row=quad*4+r (node)
            const int node = u * NPB + quad * 4 + r;
            out[(size_t)node * DOUT + jj] = d[r] + cv;
        }
    }
    __syncthreads();                    // srow reuse guard (grid-stride loop)
}

// ===================== cooperative single-kernel path =====================
__global__ __launch_bounds__(256, 4) void k_main(
    const int* __restrict__ ei, const float* __restrict__ x,
    const float* __restrict__ Wl, const float* __restrict__ Wr,
    const float* __restrict__ att, const float* __restrict__ bias,
    const float* __restrict__ Wp, const float* __restrict__ bp,
    bf16* __restrict__ WlF, bf16* __restrict__ WrF, bf16* __restrict__ WpT,
    float* __restrict__ cvec, unsigned* __restrict__ cnt,
    unsigned short* __restrict__ srcs,
    bf16* __restrict__ xl, bf16* __restrict__ xr,
    float* __restrict__ out)
{
    cg::grid_group grid = cg::this_grid();
    const int t = threadIdx.x;
    __shared__ float part[8][32];
    __shared__ __align__(16) unsigned short srow[NPB][TPAD];

    for (int b = blockIdx.x; b < PREP_UNITS; b += gridDim.x)
        prep_unit(b, t, cnt, Wl, Wr, bias, Wp, bp, WlF, WrF, WpT, cvec, part);
    __threadfence();
    grid.sync();

    for (int b = blockIdx.x; b < P1_UNITS; b += gridDim.x) {
        if (b < FILL_NB) fill_unit(b, t, ei, cnt, srcs);
        else             tf_unit(b - FILL_NB, t, x, WlF, WrF, xl, xr);
    }
    __threadfence();
    grid.sync();

    for (int u = blockIdx.x; u < AGG_NB; u += gridDim.x)
        agg_unit(u, t, srow, srcs, cnt, (const unsigned*)xl,
                 (const unsigned*)xr, att, WpT, cvec, out);
}

// ===================== fallback 3-kernel path (r20, proven) =====================
__global__ __launch_bounds__(256) void k_prep(
    unsigned* __restrict__ cnt,
    const float* __restrict__ Wl, const float* __restrict__ Wr,
    const float* __restrict__ bias, const float* __restrict__ Wp,
    const float* __restrict__ bp,
    bf16* __restrict__ WlF, bf16* __restrict__ WrF, bf16* __restrict__ WpT,
    float* __restrict__ cvec)
{
    __shared__ float part[8][32];
    prep_unit(blockIdx.x, threadIdx.x, cnt, Wl, Wr, bias, Wp, bp,
              WlF, WrF, WpT, cvec, part);
}

__global__ __launch_bounds__(256) void k_fill_tf(
    const int* __restrict__ ei, unsigned* __restrict__ cnt,
    unsigned short* __restrict__ srcs,
    const float* __restrict__ x,
    const bf16* __restrict__ WlF, const bf16* __restrict__ WrF,
    bf16* __restrict__ xl, bf16* __restrict__ xr)
{
    const int b = blockIdx.x;
    if (b < FILL_NB) fill_unit(b, threadIdx.x, ei, cnt, srcs);
    else             tf_unit(b - FILL_NB, threadIdx.x, x, WlF, WrF, xl, xr);
}

__global__ __launch_bounds__(256) void k_agg(
    const unsigned short* __restrict__ srcs, const unsigned* __restrict__ cnt,
    const unsigned* __restrict__ xl2, const unsigned* __restrict__ xr2,
    const float* __restrict__ att, const bf16* __restrict__ WpT,
    const float* __restrict__ cvec, float* __restrict__ out)
{
    __shared__ __align__(16) unsigned short srow[NPB][TPAD];
    agg_unit(blockIdx.x, threadIdx.x, srow, srcs, cnt, xl2, xr2,
             att, WpT, cvec, out);
}

extern "C" void kernel_launch(void* const* d_in, const int* in_sizes, int n_in,
                              void* d_out, int out_size, void* d_ws, size_t ws_size,
                              hipStream_t stream)
{
    const float* x    = (const float*)d_in[0];
    const int*   ei   = (const int*)d_in[1];
    const float* Wl   = (const float*)d_in[2];
    const float* Wr   = (const float*)d_in[3];
    const float* att  = (const float*)d_in[4];
    const float* bias = (const float*)d_in[5];
    const float* Wp   = (const float*)d_in[6];
    const float* bp   = (const float*)d_in[7];
    float* out = (float*)d_out;

    // workspace (~32.4 MB):
    // xl bf16[N*HC] | xr bf16[N*HC] | WlF bf16[HC*DIN] | WrF bf16[HC*DIN]
    // | WpT bf16[DOUT*HC] | cvec f32[32] | cnt u32[N] | srcs u16[N*BCAP]
    bf16* xl       = (bf16*)d_ws;
    bf16* xr       = xl + (size_t)N_NODES * HC;
    bf16* WlF      = xr + (size_t)N_NODES * HC;
    bf16* WrF      = WlF + DIN * HC;
    bf16* WpT      = WrF + DIN * HC;
    float* cvec    = (float*)(WpT + DOUT * HC);
    unsigned* cnt  = (unsigned*)(cvec + DOUT);
    unsigned short* srcs = (unsigned short*)(cnt + N_NODES);

    // one-time: can we do a cooperative launch, and at what grid size?
    static int coop_grid = -2;          // -2 uninit, -1 unsupported, >0 grid
    if (coop_grid == -2) {
        coop_grid = -1;
        int dev = 0;
        hipDeviceProp_t prop;
        if (hipGetDevice(&dev) == hipSuccess &&
            hipGetDeviceProperties(&prop, dev) == hipSuccess &&
            prop.cooperativeLaunch) {
            int maxb = 0;
            if (hipOccupancyMaxActiveBlocksPerMultiprocessor(
                    &maxb, (const void*)k_main, 256, 0) == hipSuccess && maxb > 0) {
                int g = maxb * prop.multiProcessorCount;
                if (g > P1_UNITS) g = P1_UNITS;
                coop_grid = g;
            }
        }
    }

    bool done = false;
    if (coop_grid > 0) {
        void* args[] = {
            (void*)&ei, (void*)&x, (void*)&Wl, (void*)&Wr, (void*)&att,
            (void*)&bias, (void*)&Wp, (void*)&bp,
            (void*)&WlF, (void*)&WrF, (void*)&WpT, (void*)&cvec,
            (void*)&cnt, (void*)&srcs, (void*)&xl, (void*)&xr, (void*)&out
        };
        if (hipLaunchCooperativeKernel((const void*)k_main, dim3(coop_grid),
                                       dim3(256), args, 0, stream) == hipSuccess)
            done = true;
        else
            coop_grid = -1;             // don't retry on later launches
    }
    if (!done) {                        // proven r20 3-kernel path
        k_prep<<<PREP_UNITS, 256, 0, stream>>>(
            cnt, Wl, Wr, bias, Wp, bp, WlF, WrF, WpT, cvec);
        k_fill_tf<<<P1_UNITS, 256, 0, stream>>>(ei, cnt, srcs, x,
                                                WlF, WrF, xl, xr);
        k_agg<<<AGG_NB, 256, 0, stream>>>(srcs, cnt,
            (const unsigned*)xl, (const unsigned*)xr, att, WpT, cvec, out);
    }
}

// Round 8
// 166.204 us; speedup vs baseline: 2.7304x; 2.7304x over previous
//
#include <hip/hip_runtime.h>
#include <hip/hip_bf16.h>
#include <math.h>

#define N_NODES 50000
#define N_EDGES 640000
#define HEADS 4
#define CDIM 32
#define HC 128          // HEADS*CDIM
#define DIN 128
#define DOUT 32
#define NEG_SLOPE 0.2f
#define TPAD 136        // 128 + 8 bf16 pad -> 2-way bank aliasing (free)
#define BCAP 64         // bucket capacity; P(deg>64)~1e-17 for Binom(640K,1/50K)
#define NPB 16          // nodes per k_agg block (4 waves x 4 sequential)
#define EPT 4           // edges per fill thread (625 fill blocks)
#define ZERO_NB ((N_NODES + 255) / 256)             // 196
#define WT_NB (2 * DIN * HC / 256)                  // 128
#define WPT_NB (DOUT * HC / 256)                    // 16
#define FILL_NB (N_EDGES / (256 * EPT))             // 625 (exact)
#define TF_NB ((N_NODES + 127) / 128)               // 391 (2 nodes/thread)

typedef __hip_bfloat16 bf16;
typedef __attribute__((ext_vector_type(8))) short short8;
typedef __attribute__((ext_vector_type(4))) float floatx4;
typedef __attribute__((ext_vector_type(2))) float floatx2;
typedef __attribute__((ext_vector_type(4))) unsigned short ushort4v;

static __device__ __forceinline__ float bflo(unsigned w) { return __uint_as_float(w << 16); }
static __device__ __forceinline__ float bfhi(unsigned w) { return __uint_as_float(w & 0xFFFF0000u); }
static __device__ __forceinline__ unsigned short f2bf(float f) {
    union { bf16 h; unsigned short u; } cv; cv.h = __float2bfloat16(f); return cv.u;
}

// Prep: zero cnt | Wl/Wr -> bf16 in MFMA-fragment-major order | Wp^T -> bf16
// | cvec = bias@Wp + bp (parallelized: 8x32 partials + LDS reduce).
__global__ __launch_bounds__(256) void k_prep(
    unsigned* __restrict__ cnt,
    const float* __restrict__ Wl, const float* __restrict__ Wr,
    const float* __restrict__ bias, const float* __restrict__ Wp,
    const float* __restrict__ bp,
    bf16* __restrict__ WlF, bf16* __restrict__ WrF, bf16* __restrict__ WpT,
    float* __restrict__ cvec)
{
    const int t = threadIdx.x, b = blockIdx.x;
    if (b < ZERO_NB) {
        const int i = b * 256 + t;
        if (i < N_NODES) cnt[i] = 0u;
    } else if (b < ZERO_NB + WT_NB) {
        const int i = (b - ZERO_NB) * 256 + t;      // [0, 32768)
        const int i2 = (i < DIN * HC) ? i : i - DIN * HC;
        const int c = i2 >> 7, j = i2 & 127;        // W[c][j]
        const int jt = j >> 4, m = j & 15;
        const int kk = c >> 5, quad = (c >> 3) & 3, u = c & 7;
        const int idx = (jt * 4 + kk) * 512 + (quad * 16 + m) * 8 + u;
        if (i < DIN * HC) WlF[idx] = __float2bfloat16(Wl[i2]);
        else              WrF[idx] = __float2bfloat16(Wr[i2]);
    } else if (b < ZERO_NB + WT_NB + WPT_NB) {
        const int i = (b - ZERO_NB - WT_NB) * 256 + t;  // [0, 4096)
        const int c = i >> 5, j = i & 31;           // Wp[c][j]
        WpT[j * HC + c] = __float2bfloat16(Wp[i]);
    } else {
        __shared__ float part[8][32];
        const int j = t & 31, ch = t >> 5;          // 8 chunks x 16 c's
        float v = 0.f;
        for (int c = ch * 16; c < ch * 16 + 16; c++)
            v += bias[c] * Wp[c * DOUT + j];
        part[ch][j] = v;
        __syncthreads();
        if (t < 32) {
            float s = bp[t];
            #pragma unroll
            for (int k = 0; k < 8; k++) s += part[k][t];
            cvec[t] = s;
        }
    }
}

// Fused fill + transform (r20 structure, proven): fill blocks first, tf after.
__global__ __launch_bounds__(256) void k_fill_tf(
    const int* __restrict__ ei, unsigned* __restrict__ cnt,
    unsigned short* __restrict__ srcs,  // [N_NODES][BCAP] ushort
    const float* __restrict__ x,
    const bf16* __restrict__ WlF, const bf16* __restrict__ WrF,
    bf16* __restrict__ xl, bf16* __restrict__ xr)
{
    const int t = threadIdx.x, b = blockIdx.x;

    if (b < FILL_NB) {                  // ---- bucket fill, EPT=4 edges/thread
        const int e0 = (b * 256 + t) * EPT;         // exact, no tail
        const int4 sv = *(const int4*)(ei + e0);
        const int4 dv = *(const int4*)(ei + N_EDGES + e0);
        const int s[4] = {sv.x, sv.y, sv.z, sv.w};
        const int d[4] = {dv.x, dv.y, dv.z, dv.w};
        unsigned pos[4];
        #pragma unroll
        for (int i = 0; i < EPT; i++)               // independent far-atomics
            pos[i] = atomicAdd(&cnt[d[i]], 1u);
        #pragma unroll
        for (int i = 0; i < EPT; i++)
            if (pos[i] < BCAP)
                srcs[((size_t)d[i] << 6) + pos[i]] = (unsigned short)s[i];
        return;
    }

    // ---- transform, 2 nodes/thread: each weight fragment feeds 4 MFMAs
    const int n0 = (b - FILL_NB) * 128;
    const int w = t >> 6, lane = t & 63;
    const int m = lane & 15, quad = lane >> 4;
    const int na = n0 + w * 32 + m;                 // nodes {w*32+m, +16}
    const int nb = na + 16;
    const bool va = (na < N_NODES), vb = (nb < N_NODES);

    const float* xpa = x + (size_t)(va ? na : 0) * DIN;
    const float* xpb = x + (size_t)(vb ? nb : 0) * DIN;
    short8 afa[4], afb[4];
    #pragma unroll
    for (int kk = 0; kk < 4; kk++) {
        const float4 la = *(const float4*)(xpa + kk * 32 + quad * 8);
        const float4 ha = *(const float4*)(xpa + kk * 32 + quad * 8 + 4);
        const float4 lb = *(const float4*)(xpb + kk * 32 + quad * 8);
        const float4 hb = *(const float4*)(xpb + kk * 32 + quad * 8 + 4);
        short8 va8, vb8;
        va8[0] = (short)f2bf(la.x); va8[1] = (short)f2bf(la.y);
        va8[2] = (short)f2bf(la.z); va8[3] = (short)f2bf(la.w);
        va8[4] = (short)f2bf(ha.x); va8[5] = (short)f2bf(ha.y);
        va8[6] = (short)f2bf(ha.z); va8[7] = (short)f2bf(ha.w);
        vb8[0] = (short)f2bf(lb.x); vb8[1] = (short)f2bf(lb.y);
        vb8[2] = (short)f2bf(lb.z); vb8[3] = (short)f2bf(lb.w);
        vb8[4] = (short)f2bf(hb.x); vb8[5] = (short)f2bf(hb.y);
        vb8[6] = (short)f2bf(hb.z); vb8[7] = (short)f2bf(hb.w);
        afa[kk] = va8;
        afb[kk] = vb8;
    }

    const short8* wlf = (const short8*)WlF;
    const short8* wrf = (const short8*)WrF;
    #pragma unroll
    for (int jt = 0; jt < 8; jt++) {
        floatx4 aLa = {0.f,0.f,0.f,0.f}, aLb = {0.f,0.f,0.f,0.f};
        floatx4 aRa = {0.f,0.f,0.f,0.f}, aRb = {0.f,0.f,0.f,0.f};
        #pragma unroll
        for (int kk = 0; kk < 4; kk++) {
            const short8 bl = wlf[(jt * 4 + kk) * 64 + lane];
            const short8 br = wrf[(jt * 4 + kk) * 64 + lane];
            aLa = __builtin_amdgcn_mfma_f32_16x16x32_bf16(bl, afa[kk], aLa, 0, 0, 0);
            aLb = __builtin_amdgcn_mfma_f32_16x16x32_bf16(bl, afb[kk], aLb, 0, 0, 0);
            aRa = __builtin_amdgcn_mfma_f32_16x16x32_bf16(br, afa[kk], aRa, 0, 0, 0);
            aRb = __builtin_amdgcn_mfma_f32_16x16x32_bf16(br, afb[kk], aRb, 0, 0, 0);
        }
        const int joff = jt * 16 + quad * 4;
        if (va) {
            ushort4v pl, pr;
            #pragma unroll
            for (int r = 0; r < 4; r++) { pl[r] = f2bf(aLa[r]); pr[r] = f2bf(aRa[r]); }
            *(ushort4v*)(xl + (size_t)na * HC + joff) = pl;
            *(ushort4v*)(xr + (size_t)na * HC + joff) = pr;
        }
        if (vb) {
            ushort4v pl, pr;
            #pragma unroll
            for (int r = 0; r < 4; r++) { pl[r] = f2bf(aLb[r]); pr[r] = f2bf(aRb[r]); }
            *(ushort4v*)(xl + (size_t)nb * HC + joff) = pl;
            *(ushort4v*)(xr + (size_t)nb * HC + joff) = pr;
        }
    }
}

// gather one edge's xl-row segment: broadcast src idx from lane (e&63),
// mask OOB edges to row 0 (valid, L2-hot).
static __device__ __forceinline__ uint4 gat(
    const int srcj, const int e, const int cn,
    const unsigned* __restrict__ xl2, const int hq)
{
    const int s = __shfl(srcj, e & 63, 64);
    const size_t row = (size_t)((e < cn) ? s : 0) << 6;
    return ((const uint4*)(xl2 + row))[hq];
}

// r22: packed 2xFP32 edge math — float2 (ext_vector) ops compile to CDNA
// v_pk_add_f32 / v_pk_mul_f32 / v_pk_fma_f32 (FP_CONTRACT fuses), cutting
// per-edge VALU issue slots ~40% (k_agg was VALUBusy 56% = the binding pipe).
static __device__ __forceinline__ void consume_edge(
    const uint4 bx, const int eidx, const int cn,
    const floatx2* __restrict__ xr2v, const floatx2* __restrict__ a2v,
    float& s_run, floatx2* __restrict__ acc2)
{
    floatx2 x2[4];
    x2[0] = floatx2{bflo(bx.x), bfhi(bx.x)};
    x2[1] = floatx2{bflo(bx.y), bfhi(bx.y)};
    x2[2] = floatx2{bflo(bx.z), bfhi(bx.z)};
    x2[3] = floatx2{bflo(bx.w), bfhi(bx.w)};
    floatx2 p2 = {0.f, 0.f};
    #pragma unroll
    for (int k = 0; k < 4; k++) {
        const floatx2 v = x2[k] + xr2v[k];          // pk_add
        const floatx2 vn = v * NEG_SLOPE;           // pk_mul
        floatx2 lr;
        lr.x = fmaxf(v.x, vn.x);
        lr.y = fmaxf(v.y, vn.y);
        p2 += a2v[k] * lr;                          // pk_fma (contract)
    }
    float p = p2.x + p2.y;
    p += __shfl_xor(p, 1, 64);
    p += __shfl_xor(p, 2, 64);          // per-head logit (4 hq lanes/head)
    const float e_ = (eidx < cn) ? __expf(p) : 0.f;
    s_run += e_;
    #pragma unroll
    for (int k = 0; k < 4; k++) acc2[k] += x2[k] * e_;  // pk_fma (contract)
}

// Fused logit + exp + aggregate + MFMA projection (r20 structure).
__global__ __launch_bounds__(256) void k_agg(
    const unsigned short* __restrict__ srcs, const unsigned* __restrict__ cnt,
    const unsigned* __restrict__ xl2,   // bf16 xl as uint pairs [N][64]
    const unsigned* __restrict__ xr2,   // bf16 xr as uint pairs [N][64]
    const float* __restrict__ att,
    const bf16* __restrict__ WpT,       // [DOUT][HC] bf16
    const float* __restrict__ cvec,
    float* __restrict__ out)
{
    __shared__ __align__(16) unsigned short srow[NPB][TPAD];    // 4.35 KB
    const int t = threadIdx.x;
    const int w = t >> 6, lane = t & 63;
    const int es = lane >> 4, hq = lane & 15;

    const float4 av0 = ((const float4*)att)[hq * 2];
    const float4 av1 = ((const float4*)att)[hq * 2 + 1];
    floatx2 a2[4];
    a2[0] = floatx2{av0.x, av0.y}; a2[1] = floatx2{av0.z, av0.w};
    a2[2] = floatx2{av1.x, av1.y}; a2[3] = floatx2{av1.z, av1.w};

    const int nb0 = blockIdx.x * NPB + w * 4;       // wave's 4 nodes
    const uint4 cv4 = *(const uint4*)(cnt + nb0);   // 16B-aligned (nb0 % 4 == 0)
    int cns[4];
    cns[0] = (int)(cv4.x < 64u ? cv4.x : 64u);
    cns[1] = (int)(cv4.y < 64u ? cv4.y : 64u);
    cns[2] = (int)(cv4.z < 64u ? cv4.z : 64u);
    cns[3] = (int)(cv4.w < 64u ? cv4.w : 64u);
    int srcjv[4];
    uint4 xru[4];
    #pragma unroll
    for (int ni = 0; ni < 4; ni++) {                // unguarded: srcs is [N][64]
        srcjv[ni] = (int)srcs[((size_t)(nb0 + ni) << 6) + lane];
        xru[ni] = ((const uint4*)(xr2 + (size_t)(nb0 + ni) * 64))[hq];
    }

    #pragma unroll
    for (int ni = 0; ni < 4; ni++) {
        const int cn = cns[ni];
        floatx2 xr2v[4];
        xr2v[0] = floatx2{bflo(xru[ni].x), bfhi(xru[ni].x)};
        xr2v[1] = floatx2{bflo(xru[ni].y), bfhi(xru[ni].y)};
        xr2v[2] = floatx2{bflo(xru[ni].z), bfhi(xru[ni].z)};
        xr2v[3] = floatx2{bflo(xru[ni].w), bfhi(xru[ni].w)};
        float s_run = 0.f;
        floatx2 acc2[4];
        acc2[0] = floatx2{0.f, 0.f}; acc2[1] = floatx2{0.f, 0.f};
        acc2[2] = floatx2{0.f, 0.f}; acc2[3] = floatx2{0.f, 0.f};
        const int sj = srcjv[ni];

        uint4 b0 = gat(sj, es,      cn, xl2, hq);   // depth-4 prologue
        uint4 b1 = gat(sj, es + 4,  cn, xl2, hq);
        uint4 b2 = gat(sj, es + 8,  cn, xl2, hq);
        uint4 b3 = gat(sj, es + 12, cn, xl2, hq);
        for (int i = 0; i < cn; i += 16) {
            const bool more = (i + 16 < cn);        // wave-uniform
            consume_edge(b0, i + es,      cn, xr2v, a2, s_run, acc2);
            if (more) b0 = gat(sj, i + 16 + es, cn, xl2, hq);
            consume_edge(b1, i + es + 4,  cn, xr2v, a2, s_run, acc2);
            if (more) b1 = gat(sj, i + 20 + es, cn, xl2, hq);
            consume_edge(b2, i + es + 8,  cn, xr2v, a2, s_run, acc2);
            if (more) b2 = gat(sj, i + 24 + es, cn, xl2, hq);
            consume_edge(b3, i + es + 12, cn, xr2v, a2, s_run, acc2);
            if (more) b3 = gat(sj, i + 28 + es, cn, xl2, hq);
        }
        // combine the 4 edge slots
        s_run += __shfl_xor(s_run, 16, 64);
        s_run += __shfl_xor(s_run, 32, 64);
        #pragma unroll
        for (int k = 0; k < 4; k++) {
            acc2[k].x += __shfl_xor(acc2[k].x, 16, 64);
            acc2[k].x += __shfl_xor(acc2[k].x, 32, 64);
            acc2[k].y += __shfl_xor(acc2[k].y, 16, 64);
            acc2[k].y += __shfl_xor(acc2[k].y, 32, 64);
        }
        const float rden = 1.f / (s_run + 1e-16f);

        if (es == 0) {                  // lane hq stores cols 8hq..8hq+7 (16B)
            union { unsigned short s[8]; uint4 v; } pk;
            #pragma unroll
            for (int k = 0; k < 4; k++) {
                pk.s[2 * k]     = f2bf(acc2[k].x * rden);
                pk.s[2 * k + 1] = f2bf(acc2[k].y * rden);
            }
            *(uint4*)&srow[w * 4 + ni][hq * 8] = pk.v;
        }
    }
    __syncthreads();

    // ---- MFMA projection: D[16 nodes][32 cols] = srow @ Wp, j-tile = w
    if (w < 2) {
        const int m = lane & 15, quad = lane >> 4;
        short8 af[4];
        #pragma unroll
        for (int kk = 0; kk < 4; kk++)      // A row = node m, k = kk*32+quad*8
            af[kk] = *(const short8*)&srow[m][kk * 32 + quad * 8];
        floatx4 d = {0.f, 0.f, 0.f, 0.f};
        #pragma unroll
        for (int kk = 0; kk < 4; kk++) {
            const short8 bfr = *(const short8*)(WpT + (w * 16 + m) * HC + kk * 32 + quad * 8);
            d = __builtin_amdgcn_mfma_f32_16x16x32_bf16(af[kk], bfr, d, 0, 0, 0);
        }
        const int jj = w * 16 + m;
        const float cv = cvec[jj];
        #pragma unroll
        for (int r = 0; r < 4; r++) {       // D: col=m (j), row=quad*4+r (node)
            const int node = blockIdx.x * NPB + quad * 4 + r;
            out[(size_t)node * DOUT + jj] = d[r] + cv;
        }
    }
}

extern "C" void kernel_launch(void* const* d_in, const int* in_sizes, int n_in,
                              void* d_out, int out_size, void* d_ws, size_t ws_size,
                              hipStream_t stream)
{
    const float* x    = (const float*)d_in[0];
    const int*   ei   = (const int*)d_in[1];
    const float* Wl   = (const float*)d_in[2];
    const float* Wr   = (const float*)d_in[3];
    const float* att  = (const float*)d_in[4];
    const float* bias = (const float*)d_in[5];
    const float* Wp   = (const float*)d_in[6];
    const float* bp   = (const float*)d_in[7];
    float* out = (float*)d_out;

    // workspace (~32.4 MB):
    // xl bf16[N*HC] | xr bf16[N*HC] | WlF bf16[HC*DIN] | WrF bf16[HC*DIN]
    // | WpT bf16[DOUT*HC] | cvec f32[32] | cnt u32[N] | srcs u16[N*BCAP]
    bf16* xl       = (bf16*)d_ws;
    bf16* xr       = xl + (size_t)N_NODES * HC;
    bf16* WlF      = xr + (size_t)N_NODES * HC;
    bf16* WrF      = WlF + DIN * HC;
    bf16* WpT      = WrF + DIN * HC;
    float* cvec    = (float*)(WpT + DOUT * HC);
    unsigned* cnt  = (unsigned*)(cvec + DOUT);
    unsigned short* srcs = (unsigned short*)(cnt + N_NODES);

    k_prep<<<ZERO_NB + WT_NB + WPT_NB + 1, 256, 0, stream>>>(
        cnt, Wl, Wr, bias, Wp, bp, WlF, WrF, WpT, cvec);
    k_fill_tf<<<FILL_NB + TF_NB, 256, 0, stream>>>(ei, cnt, srcs, x,
                                                   WlF, WrF, xl, xr);
    k_agg<<<N_NODES / NPB, 256, 0, stream>>>(srcs, cnt,
        (const unsigned*)xl, (const unsigned*)xr, att, WpT, cvec, out);
}